// Round 1
// baseline (151.914 us; speedup 1.0000x reference)
//
#include <hip/hip_runtime.h>
#include <math.h>

#define NG 4096
#define WI 80
#define HI 80
#define NPIX (WI*HI)
#define FOCAL 40.0f
#define LIM 1.3f

#define SH_C0 0.28209479177387814f
#define SH_C1 0.4886025119029199f

// ws layout (float slots of NG each):
// 0: depth | 1..9: gx,gy,ca,cb,cc,op,r,g,b (unsorted) | 10: rank (int) | 11..19: sorted gx..b

__global__ __launch_bounds__(256) void prep_k(
    const float* __restrict__ means, const float* __restrict__ sh,
    const int* __restrict__ shidx, const int* __restrict__ gidx,
    const float* __restrict__ opac, const float* __restrict__ scales,
    const float* __restrict__ sfac, const float* __restrict__ rots,
    const float* __restrict__ ext, float* __restrict__ ws,
    float* __restrict__ radii_out)
{
  int i = blockIdx.x*blockDim.x + threadIdx.x;
  if (i >= NG) return;
  float e0=ext[0], e1=ext[1], e2=ext[2];
  float e4=ext[4], e5=ext[5], e6=ext[6];
  float e8=ext[8], e9=ext[9], e10=ext[10];
  float e12=ext[12], e13=ext[13], e14=ext[14];
  float m0=means[3*i+0], m1=means[3*i+1], m2=means[3*i+2];
  // p_view = m @ R3 + t3  (row-vector convention)
  float tx = m0*e0 + m1*e4 + m2*e8  + e12;
  float ty = m0*e1 + m1*e5 + m2*e9  + e13;
  float tz = m0*e2 + m1*e6 + m2*e10 + e14;
  bool infront = tz > 0.2f;
  float tzs = infront ? tz : 1.0f;
  float inv_tzs = 1.0f / tzs;
  // TANX = TANY = 1, W = H = 80
  float gx = ((tx*inv_tzs + 1.0f)*WI - 1.0f)*0.5f;
  float gy = ((ty*inv_tzs + 1.0f)*HI - 1.0f)*0.5f;

  int gi = gidx[i];
  float sf = sfac[i];
  float s0 = scales[3*gi+0]*sf, s1 = scales[3*gi+1]*sf, s2 = scales[3*gi+2]*sf;
  float qw = rots[4*gi+0], qx = rots[4*gi+1], qy = rots[4*gi+2], qz = rots[4*gi+3];
  float qinv = rsqrtf(qw*qw+qx*qx+qy*qy+qz*qz);
  qw*=qinv; qx*=qinv; qy*=qinv; qz*=qinv;
  float r00 = 1.0f - 2.0f*(qy*qy+qz*qz);
  float r01 = 2.0f*(qx*qy - qw*qz);
  float r02 = 2.0f*(qx*qz + qw*qy);
  float r10 = 2.0f*(qx*qy + qw*qz);
  float r11 = 1.0f - 2.0f*(qx*qx+qz*qz);
  float r12 = 2.0f*(qy*qz - qw*qx);
  float r20 = 2.0f*(qx*qz - qw*qy);
  float r21 = 2.0f*(qy*qz + qw*qx);
  float r22 = 1.0f - 2.0f*(qx*qx+qy*qy);
  float v0 = s0*s0, v1 = s1*s1, v2 = s2*s2;
  // cov3D = R diag(v) R^T
  float C00 = r00*r00*v0 + r01*r01*v1 + r02*r02*v2;
  float C01 = r00*r10*v0 + r01*r11*v1 + r02*r12*v2;
  float C02 = r00*r20*v0 + r01*r21*v1 + r02*r22*v2;
  float C11 = r10*r10*v0 + r11*r11*v1 + r12*r12*v2;
  float C12 = r10*r20*v0 + r11*r21*v1 + r12*r22*v2;
  float C22 = r20*r20*v0 + r21*r21*v1 + r22*r22*v2;
  // cov_cam = Wm C Wm^T, Wm = R3^T -> Wm[a][b] = ext[b*4+a]
  float W0x=e0, W0y=e4, W0z=e8;
  float W1x=e1, W1y=e5, W1z=e9;
  float W2x=e2, W2y=e6, W2z=e10;
  float B00 = W0x*C00 + W0y*C01 + W0z*C02;
  float B01 = W0x*C01 + W0y*C11 + W0z*C12;
  float B02 = W0x*C02 + W0y*C12 + W0z*C22;
  float B10 = W1x*C00 + W1y*C01 + W1z*C02;
  float B11 = W1x*C01 + W1y*C11 + W1z*C12;
  float B12 = W1x*C02 + W1y*C12 + W1z*C22;
  float B20 = W2x*C00 + W2y*C01 + W2z*C02;
  float B21 = W2x*C01 + W2y*C11 + W2z*C12;
  float B22 = W2x*C02 + W2y*C12 + W2z*C22;
  float V00 = B00*W0x + B01*W0y + B02*W0z;
  float V01 = B00*W1x + B01*W1y + B02*W1z;
  float V02 = B00*W2x + B01*W2y + B02*W2z;
  float V11 = B10*W1x + B11*W1y + B12*W1z;
  float V12 = B10*W2x + B11*W2y + B12*W2z;
  float V22 = B20*W2x + B21*W2y + B22*W2z;
  // Jacobian
  float txz = tx*inv_tzs, tyz = ty*inv_tzs;
  float txc = fminf(fmaxf(txz, -LIM), LIM) * tzs;
  float tyc = fminf(fmaxf(tyz, -LIM), LIM) * tzs;
  float jx  = FOCAL*inv_tzs;
  float jy  = FOCAL*inv_tzs;
  float jz0 = -FOCAL*txc*inv_tzs*inv_tzs;
  float jz1 = -FOCAL*tyc*inv_tzs*inv_tzs;
  float c00 = jx*jx*V00 + 2.0f*jx*jz0*V02 + jz0*jz0*V22;
  float c01 = jx*jy*V01 + jx*jz1*V02 + jz0*jy*V12 + jz0*jz1*V22;
  float c11 = jy*jy*V11 + 2.0f*jy*jz1*V12 + jz1*jz1*V22;
  float a = c00 + 0.3f;
  float b = c01;
  float c = c11 + 0.3f;
  float det = a*c - b*b;
  bool valid = infront && (det > 0.0f);
  float dets = (det != 0.0f) ? det : 1.0f;
  float ca = c/dets, cb = -b/dets, cc = a/dets;
  float mid = 0.5f*(a+c);
  float lam1 = mid + sqrtf(fmaxf(0.1f, mid*mid - det));
  float radf = valid ? ceilf(3.0f*sqrtf(lam1)) : 0.0f;
  // campos = inv(extrinsic)[3,:3] (rigid): campos[k] = -(t . R[k,:])
  float cp0 = -(e12*e0 + e13*e1 + e14*e2);
  float cp1 = -(e12*e4 + e13*e5 + e14*e6);
  float cp2 = -(e12*e8 + e13*e9 + e14*e10);
  float dx0 = m0-cp0, dy0 = m1-cp1, dz0 = m2-cp2;
  float dn = rsqrtf(dx0*dx0+dy0*dy0+dz0*dz0);
  float x = dx0*dn, y = dy0*dn, z = dz0*dn;
  float xx=x*x, yy=y*y, zz=z*z;
  float xy=x*y, yz=y*z, xz=x*z;
  float bf[16];
  bf[0]  = SH_C0;
  bf[1]  = -SH_C1*y;
  bf[2]  =  SH_C1*z;
  bf[3]  = -SH_C1*x;
  bf[4]  =  1.0925484305920792f*xy;
  bf[5]  = -1.0925484305920792f*yz;
  bf[6]  =  0.31539156525252005f*(2.0f*zz-xx-yy);
  bf[7]  = -1.0925484305920792f*xz;
  bf[8]  =  0.5462742152960396f*(xx-yy);
  bf[9]  = -0.5900435899266435f*y*(3.0f*xx-yy);
  bf[10] =  2.890611442640554f*xy*z;
  bf[11] = -0.4570457994644658f*y*(4.0f*zz-xx-yy);
  bf[12] =  0.3731763325901154f*z*(2.0f*zz-3.0f*xx-3.0f*yy);
  bf[13] = -0.4570457994644658f*x*(4.0f*zz-xx-yy);
  bf[14] =  1.445305721320277f*z*(xx-yy);
  bf[15] = -0.5900435899266435f*x*(xx-yy-3.0f*zz);
  const float* S = sh + (long)shidx[i]*48;
  float cr=0.f, cg=0.f, cbl=0.f;
  #pragma unroll
  for (int j=0;j<16;j++) {
    float w = bf[j];
    cr  += w*S[j*3+0];
    cg  += w*S[j*3+1];
    cbl += w*S[j*3+2];
  }
  cr  = fmaxf(cr +0.5f, 0.0f);
  cg  = fmaxf(cg +0.5f, 0.0f);
  cbl = fmaxf(cbl+0.5f, 0.0f);

  float op = valid ? opac[i] : 0.0f;
  float depth = valid ? tz : __builtin_inff();
  ws[0*NG+i]=depth;
  ws[1*NG+i]=gx;  ws[2*NG+i]=gy;
  ws[3*NG+i]=ca;  ws[4*NG+i]=cb;  ws[5*NG+i]=cc;
  ws[6*NG+i]=op;
  ws[7*NG+i]=cr;  ws[8*NG+i]=cg;  ws[9*NG+i]=cbl;
  ((int*)ws)[10*NG+i] = 0;          // zero rank for atomic accumulation
  radii_out[i] = radf;              // int32 reference values, written as floats
}

// O(N^2) stable rank: rank[i] = #{j : d_j < d_i || (d_j == d_i && j < i)}
__global__ __launch_bounds__(256) void rank_k(const float* __restrict__ ws, int* __restrict__ rank)
{
  __shared__ float dj[256];
  int i = blockIdx.x*256 + threadIdx.x;
  int jbase = blockIdx.y*256;
  float di = ws[i];
  dj[threadIdx.x] = ws[jbase + threadIdx.x];
  __syncthreads();
  int cnt = 0;
  #pragma unroll 8
  for (int j=0;j<256;j++) {
    float d = dj[j];
    cnt += (d < di) || (d == di && (jbase+j) < i);
  }
  atomicAdd(&rank[i], cnt);
}

__global__ __launch_bounds__(256) void scatter_k(const float* __restrict__ ws,
                                                 const int* __restrict__ rank,
                                                 float* __restrict__ sorted)
{
  int i = blockIdx.x*256 + threadIdx.x;
  int r = rank[i];
  #pragma unroll
  for (int a=0;a<9;a++)
    sorted[a*NG + r] = ws[(1+a)*NG + i];
}

// One wave per pixel; 64 gaussians per step via wave prefix-product scan.
__global__ __launch_bounds__(256) void composite_k(const float* __restrict__ sg,
                                                   const float* __restrict__ bg,
                                                   float* __restrict__ out)
{
  __shared__ float lds[9][256];
  int wave = threadIdx.x >> 6;
  int lane = threadIdx.x & 63;
  int p = blockIdx.x*4 + wave;
  float px = (float)(p % WI);
  float py = (float)(p / WI);
  float T = 1.0f;
  float accr=0.f, accg=0.f, accb=0.f;
  for (int chunk=0; chunk<16; ++chunk) {
    int base = chunk*256;
    #pragma unroll
    for (int aq=0; aq<9; ++aq)
      lds[aq][threadIdx.x] = sg[aq*NG + base + threadIdx.x];
    __syncthreads();
    if (T >= 1e-4f) {   // wave-uniform early-out (matches reference cutoff to <1e-4 abs)
      #pragma unroll
      for (int sub=0; sub<4; ++sub) {
        int l = sub*64 + lane;
        float dx = lds[0][l] - px;
        float dy = lds[1][l] - py;
        float ca = lds[2][l], cb = lds[3][l], cc = lds[4][l], op = lds[5][l];
        float power = -0.5f*(ca*dx*dx + cc*dy*dy) - cb*dx*dy;
        float alpha = 0.0f;
        if (power <= 0.0f) {
          float av = fminf(0.99f, op*__expf(power));
          if (av >= (1.0f/255.0f)) alpha = av;
        }
        float om = 1.0f - alpha;
        float incl = om;
        #pragma unroll
        for (int d=1; d<64; d<<=1) {
          float up = __shfl_up(incl, (unsigned)d, 64);
          if (lane >= d) incl *= up;
        }
        float excl = __shfl_up(incl, 1u, 64);
        if (lane == 0) excl = 1.0f;
        float wgt = alpha * excl * T;
        accr += wgt*lds[6][l];
        accg += wgt*lds[7][l];
        accb += wgt*lds[8][l];
        T *= __shfl(incl, 63, 64);
      }
    }
    __syncthreads();
  }
  #pragma unroll
  for (int d=1; d<64; d<<=1) {
    accr += __shfl_xor(accr, d, 64);
    accg += __shfl_xor(accg, d, 64);
    accb += __shfl_xor(accb, d, 64);
  }
  if (lane == 0) {
    out[0*NPIX+p] = accr + T*bg[0];
    out[1*NPIX+p] = accg + T*bg[1];
    out[2*NPIX+p] = accb + T*bg[2];
  }
}

extern "C" void kernel_launch(void* const* d_in, const int* in_sizes, int n_in,
                              void* d_out, int out_size, void* d_ws, size_t ws_size,
                              hipStream_t stream) {
  const float* means  = (const float*)d_in[0];
  const float* sh     = (const float*)d_in[1];
  const int*   shidx  = (const int*)  d_in[2];
  const int*   gidx   = (const int*)  d_in[3];
  const float* opac   = (const float*)d_in[4];
  const float* scales = (const float*)d_in[5];
  const float* sfac   = (const float*)d_in[6];
  const float* rots   = (const float*)d_in[7];
  const float* ext    = (const float*)d_in[8];
  const float* bg     = (const float*)d_in[9];
  float* out = (float*)d_out;
  float* ws  = (float*)d_ws;

  prep_k<<<NG/256, 256, 0, stream>>>(means, sh, shidx, gidx, opac, scales, sfac,
                                     rots, ext, ws, out + 3*NPIX);
  dim3 rg(NG/256, NG/256);
  rank_k<<<rg, 256, 0, stream>>>(ws, (int*)(ws + 10*NG));
  scatter_k<<<NG/256, 256, 0, stream>>>(ws, (const int*)(ws + 10*NG), ws + 11*NG);
  composite_k<<<NPIX/4, 256, 0, stream>>>(ws + 11*NG, bg, out);
}